// Round 12
// baseline (136.013 us; speedup 1.0000x reference)
//
#include <hip/hip_runtime.h>
#include <math.h>

#define B_   8
#define CIN  256
#define COUT 256
#define H_   64
#define W_   64
#define HO   62
#define WO   62
#define SDIM 512

// convout padded: [b][co][62][64] bf16
#define CSTRIDE 64

typedef __attribute__((ext_vector_type(8))) short bf16x8;
typedef __attribute__((ext_vector_type(4))) float f32x4;

__device__ __forceinline__ unsigned short f2bf(float f) {
    unsigned int u = __float_as_uint(f);
    u += 0x7fffu + ((u >> 16) & 1u);
    return (unsigned short)(u >> 16);
}
__device__ __forceinline__ float bf2f(unsigned short h) {
    return __uint_as_float(((unsigned int)h) << 16);
}

// ws layout (floats):
// s:       [0, 2048)
// dm:      [2048, 4096)
// wsq:     [4096, 69632)
// wh:      [69632, 364544)     (9*256*256 ushort, hi only)
// zpage:   [364544, 365056)    (512 floats, zeroed by mod_kernel each launch)
// xh:      [659456, 4853760)   (8*64*64*256 ushort)
// convout: [9048064, 13111296) (8*256*62*64 ushort)

__global__ void mod_kernel(const float* __restrict__ style, const float* __restrict__ mod_w,
                           const float* __restrict__ mod_b, float* __restrict__ s_out,
                           float* __restrict__ zpage) {
    if (blockIdx.x == 0) {
        zpage[threadIdx.x] = 0.f;
        zpage[threadIdx.x + 256] = 0.f;
    }
    int wid = blockIdx.x * 4 + (threadIdx.x >> 6);
    int lane = threadIdx.x & 63;
    int b = wid >> 8, ci = wid & 255;
    float acc = 0.f;
    const float* st = style + b * SDIM;
    const float* mw = mod_w + ci * SDIM;
    for (int i = 0; i < SDIM; i += 64) acc += st[i + lane] * mw[i + lane];
    for (int m = 32; m >= 1; m >>= 1) acc += __shfl_xor(acc, m, 64);
    if (lane == 0) s_out[wid] = acc * 0.04419417382415922f + mod_b[ci]; // 1/sqrt(512)
}

__global__ void wsplit_kernel(const float* __restrict__ cw, float* __restrict__ wsq,
                              unsigned short* __restrict__ wh) {
    int idx = blockIdx.x * blockDim.x + threadIdx.x; // co*256+ci
    int co = idx >> 8, ci = idx & 255;
    const float* p = cw + (size_t)idx * 9;
    float ss = 0.f;
#pragma unroll
    for (int k = 0; k < 9; ++k) {
        float v = p[k];
        ss += v * v;
        wh[(k * COUT + co) * CIN + ci] = f2bf(v);
    }
    wsq[idx] = ss;
}

__global__ void demod_kernel(const float* __restrict__ s_in, const float* __restrict__ wsq,
                             float* __restrict__ dm) {
    int wid = blockIdx.x * 4 + (threadIdx.x >> 6);
    int lane = threadIdx.x & 63;
    int b = wid >> 8, co = wid & 255;
    float acc = 0.f;
    for (int i = 0; i < CIN; i += 64) {
        float sv = s_in[b * CIN + i + lane];
        acc += sv * sv * wsq[co * CIN + i + lane];
    }
    for (int m = 32; m >= 1; m >>= 1) acc += __shfl_xor(acc, m, 64);
    if (lane == 0) {
        const float scale = 0.020833333333333332f; // 1/48 = 1/sqrt(2304)
        float demod = rsqrtf(scale * scale * acc + 1e-8f);
        dm[wid] = demod * scale / (1.f + 1e-8f);
    }
}

// Transpose+scale: x[b][ci][y][x] f32 -> xh[b][y][x][ci] bf16.
__global__ __launch_bounds__(256) void xsplit_kernel(
        const float* __restrict__ x, const float* __restrict__ s_in,
        unsigned short* __restrict__ xh) {
    __shared__ float tile[128 * 65];
    __shared__ float s_loc[256];
    int b = blockIdx.x >> 6;
    int y = blockIdx.x & 63;
    int tid = threadIdx.x;
    s_loc[tid] = s_in[(b << 8) + tid];
    __syncthreads();
    for (int half = 0; half < 2; ++half) {
        int cb = half << 7;
        for (int f = tid; f < 2048; f += 256) {
            int ci = f >> 4, x4 = (f & 15) << 2;
            float4 v = *(const float4*)(x + ((((size_t)b << 8) + cb + ci) << 12) + (y << 6) + x4);
            float sv = s_loc[cb + ci];
            float* t = tile + ci * 65 + x4;
            t[0] = v.x * sv; t[1] = v.y * sv; t[2] = v.z * sv; t[3] = v.w * sv;
        }
        __syncthreads();
        for (int g = tid; g < 1024; g += 256) {
            int c = g & 15, xx = g >> 4;   // c: 8-ci chunk, xx: x position
            unsigned int hw[4];
#pragma unroll
            for (int q = 0; q < 4; ++q) {
                float v0 = tile[(c * 8 + 2 * q) * 65 + xx];
                float v1 = tile[(c * 8 + 2 * q + 1) * 65 + xx];
                hw[q] = (unsigned int)f2bf(v0) | ((unsigned int)f2bf(v1) << 16);
            }
            int o = ((((b << 6) + y) << 6) + xx) * 256 + cb + (c << 3);
            *(uint4*)(xh + o) = make_uint4(hw[0], hw[1], hw[2], hw[3]);
        }
        __syncthreads();
    }
}

// DMA staging helpers (global_load_lds, width 16): linear LDS dest, source
// carries the XOR bank-swizzle (pre-swizzled-source pattern).
__device__ __forceinline__ void stage_b(const unsigned short* wh, const int* bsrc,
                                        short* dst, int tid, int kyci) {
#pragma unroll
    for (int j = 0; j < 6; ++j)
        __builtin_amdgcn_global_load_lds(
            (const __attribute__((address_space(1))) unsigned int*)(wh + bsrc[j] + kyci),
            (__attribute__((address_space(3))) unsigned int*)(dst + ((tid + (j << 8)) << 3)),
            16, 0, 0);
}
__device__ __forceinline__ void stage_a(const unsigned short* a0, const unsigned short* a1,
                                        const unsigned short* a2, short* dst, int tid, int ci0) {
    __builtin_amdgcn_global_load_lds(
        (const __attribute__((address_space(1))) unsigned int*)(a0 + ci0),
        (__attribute__((address_space(3))) unsigned int*)(dst + (tid << 3)), 16, 0, 0);
    __builtin_amdgcn_global_load_lds(
        (const __attribute__((address_space(1))) unsigned int*)(a1 + ci0),
        (__attribute__((address_space(3))) unsigned int*)(dst + ((tid + 256) << 3)), 16, 0, 0);
    __builtin_amdgcn_global_load_lds(
        (const __attribute__((address_space(1))) unsigned int*)(a2 + ci0),
        (__attribute__((address_space(3))) unsigned int*)(dst + ((tid + 512) << 3)), 16, 0, 0);
}

// compute one ky-phase (static KY): 3 kx * 4 nt * 4 yr MFMAs (hi-only)
template<int KY>
__device__ __forceinline__ void conv_compute(const short* Ah, const short* Bb,
        f32x4 (&acc)[4][4], int lrow, int lch, int wy, int wc) {
#pragma unroll
    for (int kx = 0; kx < 3; ++kx) {
        int colL = lrow + kx;
        int asw = (lch ^ ((colL >> 1) & 3)) << 3;
        bf16x8 ahf[4];
#pragma unroll
        for (int yr = 0; yr < 4; ++yr) {
            int rr = wy * 4 + yr + KY;
            ahf[yr] = *(const bf16x8*)(Ah + (rr * 18 + colL) * 32 + asw);
        }
#pragma unroll
        for (int nt = 0; nt < 4; ++nt) {
            int col = wc * 64 + nt * 16 + lrow;
            int boff = (kx << 12) + (col << 5) + ((lch ^ ((col >> 1) & 3)) << 3);
            bf16x8 bhf = *(const bf16x8*)(Bb + boff);
#pragma unroll
            for (int yr = 0; yr < 4; ++yr)
                acc[yr][nt] = __builtin_amdgcn_mfma_f32_16x16x32_bf16(ahf[yr], bhf, acc[yr][nt], 0, 0, 0);
        }
    }
}

// Implicit-GEMM modulated conv, single-pass bf16 MFMA (ah*bh), async
// double-buffered staging via global_load_lds (no VGPR round-trip).
// LDS: A0/A1 768 slots, B0/B1 1536 slots, 16B each = 73728 B -> 2 blocks/CU.
// NOTE: no pointer-arrays into LDS (addrspacecast static-init bug) — ternary
// selects on the ping-pong bit instead.
__global__ __launch_bounds__(256) void conv_mfma(
        const unsigned short* __restrict__ xh,
        const unsigned short* __restrict__ wh,
        const unsigned short* __restrict__ zpage,
        const float* __restrict__ dm,
        const float* __restrict__ bias, unsigned short* __restrict__ convout) {
    extern __shared__ short lds[];

    int tid = threadIdx.x;
    int b = blockIdx.z;
    int co0 = blockIdx.y << 7;
    int sx = blockIdx.x & 3, sy = blockIdx.x >> 2;
    int x0 = sx << 4, y0 = sy << 3;
    int wid = tid >> 6, lane = tid & 63;
    int wy = wid >> 1, wc = wid & 1;
    int lrow = lane & 15, lch = lane >> 4;

    // B source offsets (ushort idx into wh). Slot u = tid+j*256 holds chunk
    // (u&3)^sw(co) of (kx,co), so reads at slot (kx*128+co)*4 + (lch^sw) get lch.
    int bsrc[6];
#pragma unroll
    for (int j = 0; j < 6; ++j) {
        int u = tid + (j << 8);
        int chunk = u & 3;
        int co = (u >> 2) & 127;
        int kx = u >> 9;
        int cs = chunk ^ ((co >> 1) & 3);
        bsrc[j] = (kx << 16) + ((co0 + co) << 8) + (cs << 3);
    }
    // A source pointers. Slot e = tid+k*256 (<720 real, rest pad) holds chunk
    // (e&3)^sw(col) of (row,col); OOB/pad lanes read the zero page.
    const unsigned short* ap0;
    const unsigned short* ap1;
    const unsigned short* ap2;
#pragma unroll
    for (int k = 0; k < 3; ++k) {
        int u = tid + (k << 8);
        int t2 = u >> 2;
        int col = t2 % 18, row = t2 / 18;
        int yy = y0 + row, xx = x0 + col;
        bool ok = (u < 720) && (yy < 64) && (xx < 64);
        int cs = (u & 3) ^ ((col >> 1) & 3);
        const unsigned short* p = ok ? xh + ((((b << 6) + yy) << 6) + xx) * 256 + (cs << 3) : zpage;
        if (k == 0) ap0 = p; else if (k == 1) ap1 = p; else ap2 = p;
    }

    f32x4 acc[4][4];
#pragma unroll
    for (int i = 0; i < 4; ++i)
#pragma unroll
        for (int j = 0; j < 4; ++j) acc[i][j] = (f32x4){0.f, 0.f, 0.f, 0.f};

    // prologue: stage ks=0 ky=0
    stage_a(ap0, ap1, ap2, lds, tid, 0);
    stage_b(wh, bsrc, lds + 12288, tid, 0);
    __syncthreads();

#pragma unroll 1
    for (int ks = 0; ks < 8; ++ks) {
        int ci0 = ks << 5;
        int ci0n = (ks + 1) << 5;   // ks=7: harmless garbage prefetch, never read
        int pb = ks & 1;
        short* Acur = lds + (pb ? 6144 : 0);
        short* Anxt = lds + (pb ? 0 : 6144);
        short* Bcur = lds + (pb ? 24576 : 12288);
        short* Balt = lds + (pb ? 12288 : 24576);
        // phase ky=0: stage ky=1 into Balt
        stage_b(wh, bsrc, Balt, tid, 196608 + ci0);
        conv_compute<0>(Acur, Bcur, acc, lrow, lch, wy, wc);
        __syncthreads();
        // phase ky=1: stage ky=2 into Bcur
        stage_b(wh, bsrc, Bcur, tid, 2 * 196608 + ci0);
        conv_compute<1>(Acur, Balt, acc, lrow, lch, wy, wc);
        __syncthreads();
        // phase ky=2: stage next-ks ky=0 into Balt, next A into Anxt
        stage_b(wh, bsrc, Balt, tid, ci0n);
        stage_a(ap0, ap1, ap2, Anxt, tid, ci0n);
        conv_compute<2>(Acur, Bcur, acc, lrow, lch, wy, wc);
        __syncthreads();
    }

    // epilogue: D row = x-pos = 4*lch + j, D col = co = 16*nt + lrow
    int xs4 = x0 + (lch << 2);
#pragma unroll
    for (int nt = 0; nt < 4; ++nt) {
        int co = co0 + wc * 64 + nt * 16 + lrow;
        float dmv = dm[(b << 8) + co];
        float bv = bias[co];
#pragma unroll
        for (int yr = 0; yr < 4; ++yr) {
            int y = y0 + wy * 4 + yr;
            if (y < HO) {
                ushort4 o;
                o.x = f2bf(acc[yr][nt][0] * dmv + bv);
                o.y = f2bf(acc[yr][nt][1] * dmv + bv);
                o.z = f2bf(acc[yr][nt][2] * dmv + bv);
                o.w = f2bf(acc[yr][nt][3] * dmv + bv);
                *(ushort4*)(convout + ((size_t)((b << 8) + co) * HO + y) * CSTRIDE + xs4) = o;
            }
        }
    }
}

// Fused upfirdn chain per (b,c) plane. 62x62 bf16 in -> 64x64 f32 out.
// (unchanged from round 7; see aliasing-safety comment there)
__global__ __launch_bounds__(256) void filter_kernel(
        const unsigned short* __restrict__ convout, const float* __restrict__ upf,
        const float* __restrict__ dnf, float* __restrict__ out) {
    __shared__ __align__(16) float lds0[13704];
    __shared__ __align__(16) float trow2[4][2][144];
    __shared__ float uf[12], df[12];
    float* cin  = lds0;
    float* bufA = lds0 + 4464;
    float* bufB = lds0;
    int tid = threadIdx.x;
    int p = blockIdx.x;
    const unsigned short* src = convout + (size_t)p * (HO * CSTRIDE);
    float* dst = out + (size_t)p * (64 * 64);
    if (tid < 12) { uf[tid] = upf[tid] * 2.f; df[tid] = dnf[tid]; }
    for (int idx = tid; idx < 62 * 16; idx += 256) {
        int y = idx >> 4, q = idx & 15;
        ushort4 v = *(const ushort4*)(src + y * CSTRIDE + q * 4);
        if (q < 15) {
            float4 f = make_float4(bf2f(v.x), bf2f(v.y), bf2f(v.z), bf2f(v.w));
            *(float4*)(cin + y * 72 + 4 + q * 4) = f;
        } else {
            *(float2*)(cin + y * 72 + 64) = make_float2(bf2f(v.x), bf2f(v.y));
        }
    }
    for (int idx = tid; idx < 62 * 8; idx += 256) {
        int y = idx >> 3, q = idx & 7;
        cin[y * 72 + (q < 4 ? q : 62 + q)] = 0.f;
    }
    for (int idx = tid; idx < 1056; idx += 256) {
        int r = idx / 132, cc = idx - r * 132;
        bufA[(r < 4 ? r : 62 + r) * 132 + cc] = 0.f;
    }
    __syncthreads();
    for (int task = tid; task < 62 * 16; task += 256) {
        int y = task >> 4, g = task & 15;
        const float* crow = cin + y * 72 + 4 * g;
        float xv[10];
#pragma unroll
        for (int t = 0; t < 10; ++t) xv[t] = crow[t];
        float* arow = bufA + (y + 4) * 132 + 8 * g;
#pragma unroll
        for (int dd = 0; dd < 4; ++dd) {
            float oe = 0.f, oo = 0.f;
#pragma unroll
            for (int v = 0; v < 6; ++v) {
                oe += uf[2 * v + 1] * xv[dd + 5 - v];
                oo += uf[2 * v] * xv[dd + 6 - v];
            }
            *(float2*)(arow + 2 * dd) = make_float2(oe, oo);
        }
    }
    __syncthreads();
    for (int idx = tid; idx < 325; idx += 256) bufB[idx] = 0.f;

    int wid = tid >> 6, lane = tid & 63;
    float* tr0 = &trow2[wid][0][0];
    float* tr1 = &trow2[wid][1][0];
    if (lane < 5) { tr0[lane] = 0.f; tr1[lane] = 0.f; }
    if (lane < 7) { tr0[133 + lane] = 0.f; tr1[133 + lane] = 0.f; }
    const float SQ2 = 1.4142135623730951f;
    float w0[7], w1[7];
#pragma unroll
    for (int d = 0; d < 7; ++d) {
        w0[d] = bufA[(wid + d) * 132 + lane];
        w1[d] = bufA[(wid + d) * 132 + lane + 64];
    }
    for (int it = 0; it < 16; ++it) {
        int n = 4 * it + wid;
        {
            float te0 = 0.f, to0 = 0.f, te1 = 0.f, to1 = 0.f;
#pragma unroll
            for (int d = 0; d < 6; ++d) { te0 += uf[11 - 2 * d] * w0[d]; te1 += uf[11 - 2 * d] * w1[d]; }
#pragma unroll
            for (int d = 1; d < 7; ++d) { to0 += uf[12 - 2 * d] * w0[d]; to1 += uf[12 - 2 * d] * w1[d]; }
            te0 = (te0 >= 0.f ? te0 : 0.2f * te0) * SQ2;
            to0 = (to0 >= 0.f ? to0 : 0.2f * to0) * SQ2;
            te1 = (te1 >= 0.f ? te1 : 0.2f * te1) * SQ2;
            to1 = (to1 >= 0.f ? to1 : 0.2f * to1) * SQ2;
            tr0[5 + lane] = te0;      tr1[5 + lane] = to0;
            tr0[69 + lane] = te1;     tr1[69 + lane] = to1;
        }
        __builtin_amdgcn_wave_barrier();
        {
            int xo = lane;
            const float2* a0 = (const float2*)&tr0[2 * xo];
            const float2* a1 = (const float2*)&tr1[2 * xo];
            float v0[12], v1[12];
#pragma unroll
            for (int q = 0; q < 6; ++q) {
                float2 u0 = a0[q], u1 = a1[q];
                v0[2 * q] = u0.x; v0[2 * q + 1] = u0.y;
                v1[2 * q] = u1.x; v1[2 * q + 1] = u1.y;
            }
            float s0 = 0.f, s1 = 0.f;
#pragma unroll
            for (int u = 0; u < 12; ++u) {
                s0 += df[u] * v0[11 - u];
                s1 += df[u] * v1[11 - u];
            }
            bufB[(2 * n + 5) * 65 + xo] = s0;
            bufB[(2 * n + 6) * 65 + xo] = s1;
        }
        if (it < 15) {
#pragma unroll
            for (int d = 0; d < 3; ++d) { w0[d] = w0[d + 4]; w1[d] = w1[d + 4]; }
#pragma unroll
            for (int d = 3; d < 7; ++d) {
                w0[d] = bufA[(n + 4 + d) * 132 + lane];
                w1[d] = bufA[(n + 4 + d) * 132 + lane + 64];
            }
        }
        if ((it & 3) == 3) __syncthreads();
        else __builtin_amdgcn_wave_barrier();
    }
    for (int idx = tid; idx < 64 * 64; idx += 256) {
        int yo = idx >> 6, xx = idx & 63;
        float acc2 = 0.f;
#pragma unroll
        for (int u = 0; u < 12; ++u) {
            int rr = 2 * yo + 6 - u;
            float v = (rr < 128) ? bufB[(rr + 5) * 65 + xx] : 0.f;
            acc2 += df[u] * v;
        }
        dst[idx] = acc2;
    }
}

extern "C" void kernel_launch(void* const* d_in, const int* in_sizes, int n_in,
                              void* d_out, int out_size, void* d_ws, size_t ws_size,
                              hipStream_t stream) {
    const float* input       = (const float*)d_in[0];
    const float* style       = (const float*)d_in[1];
    const float* conv_weight = (const float*)d_in[2];
    const float* mod_w       = (const float*)d_in[3];
    const float* mod_b       = (const float*)d_in[4];
    const float* bias        = (const float*)d_in[5];
    const float* up_filter   = (const float*)d_in[6];
    const float* down_filter = (const float*)d_in[7];
    float* ws  = (float*)d_ws;
    float* out = (float*)d_out;
    float* s_buf   = ws;
    float* dm      = ws + 2048;
    float* wsq     = ws + 4096;
    unsigned short* wh      = (unsigned short*)(ws + 69632);
    float* zpage            = ws + 364544;
    unsigned short* xh      = (unsigned short*)(ws + 659456);
    unsigned short* convout = (unsigned short*)(ws + 9048064);

    hipLaunchKernelGGL(mod_kernel, dim3(512), dim3(256), 0, stream, style, mod_w, mod_b, s_buf, zpage);
    hipLaunchKernelGGL(wsplit_kernel, dim3(256), dim3(256), 0, stream, conv_weight, wsq, wh);
    hipLaunchKernelGGL(demod_kernel, dim3(512), dim3(256), 0, stream, s_buf, wsq, dm);
    hipLaunchKernelGGL(xsplit_kernel, dim3(512), dim3(256), 0, stream, input, s_buf, xh);
    hipLaunchKernelGGL(conv_mfma, dim3(32, 2, 8), dim3(256), 73728, stream,
                       xh, wh, (const unsigned short*)zpage, dm, bias, convout);
    hipLaunchKernelGGL(filter_kernel, dim3(2048), dim3(256), 0, stream,
                       convout, up_filter, down_filter, out);
}

// Round 13
// 135.964 us; speedup vs baseline: 1.0004x; 1.0004x over previous
//
#include <hip/hip_runtime.h>
#include <math.h>

#define B_   8
#define CIN  256
#define COUT 256
#define H_   64
#define W_   64
#define HO   62
#define WO   62
#define SDIM 512

// convout padded: [b][co][62][64] bf16
#define CSTRIDE 64

typedef __attribute__((ext_vector_type(8))) short bf16x8;
typedef __attribute__((ext_vector_type(4))) float f32x4;

__device__ __forceinline__ unsigned short f2bf(float f) {
    unsigned int u = __float_as_uint(f);
    u += 0x7fffu + ((u >> 16) & 1u);
    return (unsigned short)(u >> 16);
}
__device__ __forceinline__ float bf2f(unsigned short h) {
    return __uint_as_float(((unsigned int)h) << 16);
}

// ws layout (floats):
// s:       [0, 2048)
// dm:      [2048, 4096)
// wsq:     [4096, 69632)
// wh:      [69632, 364544)     (9*256*256 ushort, hi only)
// zpage:   [364544, 365056)    (512 floats, zeroed by mod_kernel each launch)
// xh:      [659456, 4853760)   (8*64*64*256 ushort)
// convout: [9048064, 13111296) (8*256*62*64 ushort)

__global__ void mod_kernel(const float* __restrict__ style, const float* __restrict__ mod_w,
                           const float* __restrict__ mod_b, float* __restrict__ s_out,
                           float* __restrict__ zpage) {
    if (blockIdx.x == 0) {
        zpage[threadIdx.x] = 0.f;
        zpage[threadIdx.x + 256] = 0.f;
    }
    int wid = blockIdx.x * 4 + (threadIdx.x >> 6);
    int lane = threadIdx.x & 63;
    int b = wid >> 8, ci = wid & 255;
    float acc = 0.f;
    const float* st = style + b * SDIM;
    const float* mw = mod_w + ci * SDIM;
    for (int i = 0; i < SDIM; i += 64) acc += st[i + lane] * mw[i + lane];
    for (int m = 32; m >= 1; m >>= 1) acc += __shfl_xor(acc, m, 64);
    if (lane == 0) s_out[wid] = acc * 0.04419417382415922f + mod_b[ci]; // 1/sqrt(512)
}

__global__ void wsplit_kernel(const float* __restrict__ cw, float* __restrict__ wsq,
                              unsigned short* __restrict__ wh) {
    int idx = blockIdx.x * blockDim.x + threadIdx.x; // co*256+ci
    int co = idx >> 8, ci = idx & 255;
    const float* p = cw + (size_t)idx * 9;
    float ss = 0.f;
#pragma unroll
    for (int k = 0; k < 9; ++k) {
        float v = p[k];
        ss += v * v;
        wh[(k * COUT + co) * CIN + ci] = f2bf(v);
    }
    wsq[idx] = ss;
}

__global__ void demod_kernel(const float* __restrict__ s_in, const float* __restrict__ wsq,
                             float* __restrict__ dm) {
    int wid = blockIdx.x * 4 + (threadIdx.x >> 6);
    int lane = threadIdx.x & 63;
    int b = wid >> 8, co = wid & 255;
    float acc = 0.f;
    for (int i = 0; i < CIN; i += 64) {
        float sv = s_in[b * CIN + i + lane];
        acc += sv * sv * wsq[co * CIN + i + lane];
    }
    for (int m = 32; m >= 1; m >>= 1) acc += __shfl_xor(acc, m, 64);
    if (lane == 0) {
        const float scale = 0.020833333333333332f; // 1/48 = 1/sqrt(2304)
        float demod = rsqrtf(scale * scale * acc + 1e-8f);
        dm[wid] = demod * scale / (1.f + 1e-8f);
    }
}

// Transpose+scale: x[b][ci][y][x] f32 -> xh[b][y][x][ci] bf16.
__global__ __launch_bounds__(256) void xsplit_kernel(
        const float* __restrict__ x, const float* __restrict__ s_in,
        unsigned short* __restrict__ xh) {
    __shared__ float tile[128 * 65];
    __shared__ float s_loc[256];
    int b = blockIdx.x >> 6;
    int y = blockIdx.x & 63;
    int tid = threadIdx.x;
    s_loc[tid] = s_in[(b << 8) + tid];
    __syncthreads();
    for (int half = 0; half < 2; ++half) {
        int cb = half << 7;
        for (int f = tid; f < 2048; f += 256) {
            int ci = f >> 4, x4 = (f & 15) << 2;
            float4 v = *(const float4*)(x + ((((size_t)b << 8) + cb + ci) << 12) + (y << 6) + x4);
            float sv = s_loc[cb + ci];
            float* t = tile + ci * 65 + x4;
            t[0] = v.x * sv; t[1] = v.y * sv; t[2] = v.z * sv; t[3] = v.w * sv;
        }
        __syncthreads();
        for (int g = tid; g < 1024; g += 256) {
            int c = g & 15, xx = g >> 4;   // c: 8-ci chunk, xx: x position
            unsigned int hw[4];
#pragma unroll
            for (int q = 0; q < 4; ++q) {
                float v0 = tile[(c * 8 + 2 * q) * 65 + xx];
                float v1 = tile[(c * 8 + 2 * q + 1) * 65 + xx];
                hw[q] = (unsigned int)f2bf(v0) | ((unsigned int)f2bf(v1) << 16);
            }
            int o = ((((b << 6) + y) << 6) + xx) * 256 + cb + (c << 3);
            *(uint4*)(xh + o) = make_uint4(hw[0], hw[1], hw[2], hw[3]);
        }
        __syncthreads();
    }
}

// DMA staging helpers (global_load_lds, width 16): linear LDS dest, source
// carries the XOR bank-swizzle (pre-swizzled-source pattern).
__device__ __forceinline__ void stage_b(const unsigned short* wh, const int* bsrc,
                                        short* dst, int tid, int kyci) {
#pragma unroll
    for (int j = 0; j < 6; ++j)
        __builtin_amdgcn_global_load_lds(
            (const __attribute__((address_space(1))) unsigned int*)(wh + bsrc[j] + kyci),
            (__attribute__((address_space(3))) unsigned int*)(dst + ((tid + (j << 8)) << 3)),
            16, 0, 0);
}
__device__ __forceinline__ void stage_a(const unsigned short* a0, const unsigned short* a1,
                                        const unsigned short* a2, short* dst, int tid, int ci0) {
    __builtin_amdgcn_global_load_lds(
        (const __attribute__((address_space(1))) unsigned int*)(a0 + ci0),
        (__attribute__((address_space(3))) unsigned int*)(dst + (tid << 3)), 16, 0, 0);
    __builtin_amdgcn_global_load_lds(
        (const __attribute__((address_space(1))) unsigned int*)(a1 + ci0),
        (__attribute__((address_space(3))) unsigned int*)(dst + ((tid + 256) << 3)), 16, 0, 0);
    __builtin_amdgcn_global_load_lds(
        (const __attribute__((address_space(1))) unsigned int*)(a2 + ci0),
        (__attribute__((address_space(3))) unsigned int*)(dst + ((tid + 512) << 3)), 16, 0, 0);
}

// compute one ky-phase (static KY): 3 kx * 4 nt * 4 yr MFMAs (hi-only)
template<int KY>
__device__ __forceinline__ void conv_compute(const short* Ah, const short* Bb,
        f32x4 (&acc)[4][4], int lrow, int lch, int wy, int wc) {
#pragma unroll
    for (int kx = 0; kx < 3; ++kx) {
        int colL = lrow + kx;
        int asw = (lch ^ ((colL >> 1) & 3)) << 3;
        bf16x8 ahf[4];
#pragma unroll
        for (int yr = 0; yr < 4; ++yr) {
            int rr = wy * 4 + yr + KY;
            ahf[yr] = *(const bf16x8*)(Ah + (rr * 18 + colL) * 32 + asw);
        }
#pragma unroll
        for (int nt = 0; nt < 4; ++nt) {
            int col = wc * 64 + nt * 16 + lrow;
            int boff = (kx << 12) + (col << 5) + ((lch ^ ((col >> 1) & 3)) << 3);
            bf16x8 bhf = *(const bf16x8*)(Bb + boff);
#pragma unroll
            for (int yr = 0; yr < 4; ++yr)
                acc[yr][nt] = __builtin_amdgcn_mfma_f32_16x16x32_bf16(ahf[yr], bhf, acc[yr][nt], 0, 0, 0);
        }
    }
}

// Implicit-GEMM modulated conv, single-pass bf16 MFMA (ah*bh), async
// double-buffered staging via global_load_lds (no VGPR round-trip).
// LDS: A0/A1 768 slots, B0/B1 1536 slots, 16B each = 73728 B -> 2 blocks/CU.
// NOTE: no pointer-arrays into LDS (addrspacecast static-init bug) — ternary
// selects on the ping-pong bit instead.
__global__ __launch_bounds__(256) void conv_mfma(
        const unsigned short* __restrict__ xh,
        const unsigned short* __restrict__ wh,
        const unsigned short* __restrict__ zpage,
        const float* __restrict__ dm,
        const float* __restrict__ bias, unsigned short* __restrict__ convout) {
    extern __shared__ short lds[];

    int tid = threadIdx.x;
    int b = blockIdx.z;
    int co0 = blockIdx.y << 7;
    int sx = blockIdx.x & 3, sy = blockIdx.x >> 2;
    int x0 = sx << 4, y0 = sy << 3;
    int wid = tid >> 6, lane = tid & 63;
    int wy = wid >> 1, wc = wid & 1;
    int lrow = lane & 15, lch = lane >> 4;

    // B source offsets (ushort idx into wh). Slot u = tid+j*256 holds chunk
    // (u&3)^sw(co) of (kx,co), so reads at slot (kx*128+co)*4 + (lch^sw) get lch.
    int bsrc[6];
#pragma unroll
    for (int j = 0; j < 6; ++j) {
        int u = tid + (j << 8);
        int chunk = u & 3;
        int co = (u >> 2) & 127;
        int kx = u >> 9;
        int cs = chunk ^ ((co >> 1) & 3);
        bsrc[j] = (kx << 16) + ((co0 + co) << 8) + (cs << 3);
    }
    // A source pointers. Slot e = tid+k*256 (<720 real, rest pad) holds chunk
    // (e&3)^sw(col) of (row,col); OOB/pad lanes read the zero page.
    const unsigned short* ap0;
    const unsigned short* ap1;
    const unsigned short* ap2;
#pragma unroll
    for (int k = 0; k < 3; ++k) {
        int u = tid + (k << 8);
        int t2 = u >> 2;
        int col = t2 % 18, row = t2 / 18;
        int yy = y0 + row, xx = x0 + col;
        bool ok = (u < 720) && (yy < 64) && (xx < 64);
        int cs = (u & 3) ^ ((col >> 1) & 3);
        const unsigned short* p = ok ? xh + ((((b << 6) + yy) << 6) + xx) * 256 + (cs << 3) : zpage;
        if (k == 0) ap0 = p; else if (k == 1) ap1 = p; else ap2 = p;
    }

    f32x4 acc[4][4];
#pragma unroll
    for (int i = 0; i < 4; ++i)
#pragma unroll
        for (int j = 0; j < 4; ++j) acc[i][j] = (f32x4){0.f, 0.f, 0.f, 0.f};

    // prologue: stage ks=0 ky=0
    stage_a(ap0, ap1, ap2, lds, tid, 0);
    stage_b(wh, bsrc, lds + 12288, tid, 0);
    __syncthreads();

#pragma unroll 1
    for (int ks = 0; ks < 8; ++ks) {
        int ci0 = ks << 5;
        int ci0n = (ks + 1) << 5;   // ks=7: harmless garbage prefetch, never read
        int pb = ks & 1;
        short* Acur = lds + (pb ? 6144 : 0);
        short* Anxt = lds + (pb ? 0 : 6144);
        short* Bcur = lds + (pb ? 24576 : 12288);
        short* Balt = lds + (pb ? 12288 : 24576);
        // phase ky=0: stage ky=1 into Balt
        stage_b(wh, bsrc, Balt, tid, 196608 + ci0);
        conv_compute<0>(Acur, Bcur, acc, lrow, lch, wy, wc);
        __syncthreads();
        // phase ky=1: stage ky=2 into Bcur
        stage_b(wh, bsrc, Bcur, tid, 2 * 196608 + ci0);
        conv_compute<1>(Acur, Balt, acc, lrow, lch, wy, wc);
        __syncthreads();
        // phase ky=2: stage next-ks ky=0 into Balt, next A into Anxt
        stage_b(wh, bsrc, Balt, tid, ci0n);
        stage_a(ap0, ap1, ap2, Anxt, tid, ci0n);
        conv_compute<2>(Acur, Bcur, acc, lrow, lch, wy, wc);
        __syncthreads();
    }

    // epilogue: D row = x-pos = 4*lch + j, D col = co = 16*nt + lrow
    int xs4 = x0 + (lch << 2);
#pragma unroll
    for (int nt = 0; nt < 4; ++nt) {
        int co = co0 + wc * 64 + nt * 16 + lrow;
        float dmv = dm[(b << 8) + co];
        float bv = bias[co];
#pragma unroll
        for (int yr = 0; yr < 4; ++yr) {
            int y = y0 + wy * 4 + yr;
            if (y < HO) {
                ushort4 o;
                o.x = f2bf(acc[yr][nt][0] * dmv + bv);
                o.y = f2bf(acc[yr][nt][1] * dmv + bv);
                o.z = f2bf(acc[yr][nt][2] * dmv + bv);
                o.w = f2bf(acc[yr][nt][3] * dmv + bv);
                *(ushort4*)(convout + ((size_t)((b << 8) + co) * HO + y) * CSTRIDE + xs4) = o;
            }
        }
    }
}

// Fused upfirdn chain per (b,c) plane. 62x62 bf16 in -> 64x64 f32 out.
// (unchanged from round 7; see aliasing-safety comment there)
__global__ __launch_bounds__(256) void filter_kernel(
        const unsigned short* __restrict__ convout, const float* __restrict__ upf,
        const float* __restrict__ dnf, float* __restrict__ out) {
    __shared__ __align__(16) float lds0[13704];
    __shared__ __align__(16) float trow2[4][2][144];
    __shared__ float uf[12], df[12];
    float* cin  = lds0;
    float* bufA = lds0 + 4464;
    float* bufB = lds0;
    int tid = threadIdx.x;
    int p = blockIdx.x;
    const unsigned short* src = convout + (size_t)p * (HO * CSTRIDE);
    float* dst = out + (size_t)p * (64 * 64);
    if (tid < 12) { uf[tid] = upf[tid] * 2.f; df[tid] = dnf[tid]; }
    for (int idx = tid; idx < 62 * 16; idx += 256) {
        int y = idx >> 4, q = idx & 15;
        ushort4 v = *(const ushort4*)(src + y * CSTRIDE + q * 4);
        if (q < 15) {
            float4 f = make_float4(bf2f(v.x), bf2f(v.y), bf2f(v.z), bf2f(v.w));
            *(float4*)(cin + y * 72 + 4 + q * 4) = f;
        } else {
            *(float2*)(cin + y * 72 + 64) = make_float2(bf2f(v.x), bf2f(v.y));
        }
    }
    for (int idx = tid; idx < 62 * 8; idx += 256) {
        int y = idx >> 3, q = idx & 7;
        cin[y * 72 + (q < 4 ? q : 62 + q)] = 0.f;
    }
    for (int idx = tid; idx < 1056; idx += 256) {
        int r = idx / 132, cc = idx - r * 132;
        bufA[(r < 4 ? r : 62 + r) * 132 + cc] = 0.f;
    }
    __syncthreads();
    for (int task = tid; task < 62 * 16; task += 256) {
        int y = task >> 4, g = task & 15;
        const float* crow = cin + y * 72 + 4 * g;
        float xv[10];
#pragma unroll
        for (int t = 0; t < 10; ++t) xv[t] = crow[t];
        float* arow = bufA + (y + 4) * 132 + 8 * g;
#pragma unroll
        for (int dd = 0; dd < 4; ++dd) {
            float oe = 0.f, oo = 0.f;
#pragma unroll
            for (int v = 0; v < 6; ++v) {
                oe += uf[2 * v + 1] * xv[dd + 5 - v];
                oo += uf[2 * v] * xv[dd + 6 - v];
            }
            *(float2*)(arow + 2 * dd) = make_float2(oe, oo);
        }
    }
    __syncthreads();
    for (int idx = tid; idx < 325; idx += 256) bufB[idx] = 0.f;

    int wid = tid >> 6, lane = tid & 63;
    float* tr0 = &trow2[wid][0][0];
    float* tr1 = &trow2[wid][1][0];
    if (lane < 5) { tr0[lane] = 0.f; tr1[lane] = 0.f; }
    if (lane < 7) { tr0[133 + lane] = 0.f; tr1[133 + lane] = 0.f; }
    const float SQ2 = 1.4142135623730951f;
    float w0[7], w1[7];
#pragma unroll
    for (int d = 0; d < 7; ++d) {
        w0[d] = bufA[(wid + d) * 132 + lane];
        w1[d] = bufA[(wid + d) * 132 + lane + 64];
    }
    for (int it = 0; it < 16; ++it) {
        int n = 4 * it + wid;
        {
            float te0 = 0.f, to0 = 0.f, te1 = 0.f, to1 = 0.f;
#pragma unroll
            for (int d = 0; d < 6; ++d) { te0 += uf[11 - 2 * d] * w0[d]; te1 += uf[11 - 2 * d] * w1[d]; }
#pragma unroll
            for (int d = 1; d < 7; ++d) { to0 += uf[12 - 2 * d] * w0[d]; to1 += uf[12 - 2 * d] * w1[d]; }
            te0 = (te0 >= 0.f ? te0 : 0.2f * te0) * SQ2;
            to0 = (to0 >= 0.f ? to0 : 0.2f * to0) * SQ2;
            te1 = (te1 >= 0.f ? te1 : 0.2f * te1) * SQ2;
            to1 = (to1 >= 0.f ? to1 : 0.2f * to1) * SQ2;
            tr0[5 + lane] = te0;      tr1[5 + lane] = to0;
            tr0[69 + lane] = te1;     tr1[69 + lane] = to1;
        }
        __builtin_amdgcn_wave_barrier();
        {
            int xo = lane;
            const float2* a0 = (const float2*)&tr0[2 * xo];
            const float2* a1 = (const float2*)&tr1[2 * xo];
            float v0[12], v1[12];
#pragma unroll
            for (int q = 0; q < 6; ++q) {
                float2 u0 = a0[q], u1 = a1[q];
                v0[2 * q] = u0.x; v0[2 * q + 1] = u0.y;
                v1[2 * q] = u1.x; v1[2 * q + 1] = u1.y;
            }
            float s0 = 0.f, s1 = 0.f;
#pragma unroll
            for (int u = 0; u < 12; ++u) {
                s0 += df[u] * v0[11 - u];
                s1 += df[u] * v1[11 - u];
            }
            bufB[(2 * n + 5) * 65 + xo] = s0;
            bufB[(2 * n + 6) * 65 + xo] = s1;
        }
        if (it < 15) {
#pragma unroll
            for (int d = 0; d < 3; ++d) { w0[d] = w0[d + 4]; w1[d] = w1[d + 4]; }
#pragma unroll
            for (int d = 3; d < 7; ++d) {
                w0[d] = bufA[(n + 4 + d) * 132 + lane];
                w1[d] = bufA[(n + 4 + d) * 132 + lane + 64];
            }
        }
        if ((it & 3) == 3) __syncthreads();
        else __builtin_amdgcn_wave_barrier();
    }
    for (int idx = tid; idx < 64 * 64; idx += 256) {
        int yo = idx >> 6, xx = idx & 63;
        float acc2 = 0.f;
#pragma unroll
        for (int u = 0; u < 12; ++u) {
            int rr = 2 * yo + 6 - u;
            float v = (rr < 128) ? bufB[(rr + 5) * 65 + xx] : 0.f;
            acc2 += df[u] * v;
        }
        dst[idx] = acc2;
    }
}

extern "C" void kernel_launch(void* const* d_in, const int* in_sizes, int n_in,
                              void* d_out, int out_size, void* d_ws, size_t ws_size,
                              hipStream_t stream) {
    const float* input       = (const float*)d_in[0];
    const float* style       = (const float*)d_in[1];
    const float* conv_weight = (const float*)d_in[2];
    const float* mod_w       = (const float*)d_in[3];
    const float* mod_b       = (const float*)d_in[4];
    const float* bias        = (const float*)d_in[5];
    const float* up_filter   = (const float*)d_in[6];
    const float* down_filter = (const float*)d_in[7];
    float* ws  = (float*)d_ws;
    float* out = (float*)d_out;
    float* s_buf   = ws;
    float* dm      = ws + 2048;
    float* wsq     = ws + 4096;
    unsigned short* wh      = (unsigned short*)(ws + 69632);
    float* zpage            = ws + 364544;
    unsigned short* xh      = (unsigned short*)(ws + 659456);
    unsigned short* convout = (unsigned short*)(ws + 9048064);

    hipLaunchKernelGGL(mod_kernel, dim3(512), dim3(256), 0, stream, style, mod_w, mod_b, s_buf, zpage);
    hipLaunchKernelGGL(wsplit_kernel, dim3(256), dim3(256), 0, stream, conv_weight, wsq, wh);
    hipLaunchKernelGGL(demod_kernel, dim3(512), dim3(256), 0, stream, s_buf, wsq, dm);
    hipLaunchKernelGGL(xsplit_kernel, dim3(512), dim3(256), 0, stream, input, s_buf, xh);
    hipLaunchKernelGGL(conv_mfma, dim3(32, 2, 8), dim3(256), 73728, stream,
                       xh, wh, (const unsigned short*)zpage, dm, bias, convout);
    hipLaunchKernelGGL(filter_kernel, dim3(2048), dim3(256), 0, stream,
                       convout, up_filter, down_filter, out);
}

// Round 14
// 135.768 us; speedup vs baseline: 1.0018x; 1.0014x over previous
//
#include <hip/hip_runtime.h>
#include <math.h>

#define B_   8
#define CIN  256
#define COUT 256
#define H_   64
#define W_   64
#define HO   62
#define WO   62
#define SDIM 512

// convout padded: [b][co][62][64] bf16
#define CSTRIDE 64

typedef __attribute__((ext_vector_type(8))) short bf16x8;
typedef __attribute__((ext_vector_type(4))) float f32x4;

__device__ __forceinline__ unsigned short f2bf(float f) {
    unsigned int u = __float_as_uint(f);
    u += 0x7fffu + ((u >> 16) & 1u);
    return (unsigned short)(u >> 16);
}
__device__ __forceinline__ float bf2f(unsigned short h) {
    return __uint_as_float(((unsigned int)h) << 16);
}

// ws layout (floats):
// s:       [0, 2048)
// dm:      [2048, 4096)
// wsq:     [4096, 69632)
// wh:      [69632, 364544)     (9*256*256 ushort, hi only)
// zpage:   [364544, 365056)    (512 floats, zeroed by mod_kernel each launch)
// xh:      [659456, 4853760)   (8*64*64*256 ushort)
// convout: [9048064, 13111296) (8*256*62*64 ushort)

__global__ void mod_kernel(const float* __restrict__ style, const float* __restrict__ mod_w,
                           const float* __restrict__ mod_b, float* __restrict__ s_out,
                           float* __restrict__ zpage) {
    if (blockIdx.x == 0) {
        zpage[threadIdx.x] = 0.f;
        zpage[threadIdx.x + 256] = 0.f;
    }
    int wid = blockIdx.x * 4 + (threadIdx.x >> 6);
    int lane = threadIdx.x & 63;
    int b = wid >> 8, ci = wid & 255;
    float acc = 0.f;
    const float* st = style + b * SDIM;
    const float* mw = mod_w + ci * SDIM;
    for (int i = 0; i < SDIM; i += 64) acc += st[i + lane] * mw[i + lane];
    for (int m = 32; m >= 1; m >>= 1) acc += __shfl_xor(acc, m, 64);
    if (lane == 0) s_out[wid] = acc * 0.04419417382415922f + mod_b[ci]; // 1/sqrt(512)
}

__global__ void wsplit_kernel(const float* __restrict__ cw, float* __restrict__ wsq,
                              unsigned short* __restrict__ wh) {
    int idx = blockIdx.x * blockDim.x + threadIdx.x; // co*256+ci
    int co = idx >> 8, ci = idx & 255;
    const float* p = cw + (size_t)idx * 9;
    float ss = 0.f;
#pragma unroll
    for (int k = 0; k < 9; ++k) {
        float v = p[k];
        ss += v * v;
        wh[(k * COUT + co) * CIN + ci] = f2bf(v);
    }
    wsq[idx] = ss;
}

__global__ void demod_kernel(const float* __restrict__ s_in, const float* __restrict__ wsq,
                             float* __restrict__ dm) {
    int wid = blockIdx.x * 4 + (threadIdx.x >> 6);
    int lane = threadIdx.x & 63;
    int b = wid >> 8, co = wid & 255;
    float acc = 0.f;
    for (int i = 0; i < CIN; i += 64) {
        float sv = s_in[b * CIN + i + lane];
        acc += sv * sv * wsq[co * CIN + i + lane];
    }
    for (int m = 32; m >= 1; m >>= 1) acc += __shfl_xor(acc, m, 64);
    if (lane == 0) {
        const float scale = 0.020833333333333332f; // 1/48 = 1/sqrt(2304)
        float demod = rsqrtf(scale * scale * acc + 1e-8f);
        dm[wid] = demod * scale / (1.f + 1e-8f);
    }
}

// Transpose+scale: x[b][ci][y][x] f32 -> xh[b][y][x][ci] bf16.
__global__ __launch_bounds__(256) void xsplit_kernel(
        const float* __restrict__ x, const float* __restrict__ s_in,
        unsigned short* __restrict__ xh) {
    __shared__ float tile[128 * 65];
    __shared__ float s_loc[256];
    int b = blockIdx.x >> 6;
    int y = blockIdx.x & 63;
    int tid = threadIdx.x;
    s_loc[tid] = s_in[(b << 8) + tid];
    __syncthreads();
    for (int half = 0; half < 2; ++half) {
        int cb = half << 7;
        for (int f = tid; f < 2048; f += 256) {
            int ci = f >> 4, x4 = (f & 15) << 2;
            float4 v = *(const float4*)(x + ((((size_t)b << 8) + cb + ci) << 12) + (y << 6) + x4);
            float sv = s_loc[cb + ci];
            float* t = tile + ci * 65 + x4;
            t[0] = v.x * sv; t[1] = v.y * sv; t[2] = v.z * sv; t[3] = v.w * sv;
        }
        __syncthreads();
        for (int g = tid; g < 1024; g += 256) {
            int c = g & 15, xx = g >> 4;   // c: 8-ci chunk, xx: x position
            unsigned int hw[4];
#pragma unroll
            for (int q = 0; q < 4; ++q) {
                float v0 = tile[(c * 8 + 2 * q) * 65 + xx];
                float v1 = tile[(c * 8 + 2 * q + 1) * 65 + xx];
                hw[q] = (unsigned int)f2bf(v0) | ((unsigned int)f2bf(v1) << 16);
            }
            int o = ((((b << 6) + y) << 6) + xx) * 256 + cb + (c << 3);
            *(uint4*)(xh + o) = make_uint4(hw[0], hw[1], hw[2], hw[3]);
        }
        __syncthreads();
    }
}

// DMA staging helpers (global_load_lds, width 16): linear LDS dest, source
// carries the XOR bank-swizzle (pre-swizzled-source pattern).
__device__ __forceinline__ void stage_b(const unsigned short* wh, const int* bsrc,
                                        short* dst, int tid, int kyci) {
#pragma unroll
    for (int j = 0; j < 6; ++j)
        __builtin_amdgcn_global_load_lds(
            (const __attribute__((address_space(1))) unsigned int*)(wh + bsrc[j] + kyci),
            (__attribute__((address_space(3))) unsigned int*)(dst + ((tid + (j << 8)) << 3)),
            16, 0, 0);
}
__device__ __forceinline__ void stage_a(const unsigned short* a0, const unsigned short* a1,
                                        const unsigned short* a2, short* dst, int tid, int ci0) {
    __builtin_amdgcn_global_load_lds(
        (const __attribute__((address_space(1))) unsigned int*)(a0 + ci0),
        (__attribute__((address_space(3))) unsigned int*)(dst + (tid << 3)), 16, 0, 0);
    __builtin_amdgcn_global_load_lds(
        (const __attribute__((address_space(1))) unsigned int*)(a1 + ci0),
        (__attribute__((address_space(3))) unsigned int*)(dst + ((tid + 256) << 3)), 16, 0, 0);
    __builtin_amdgcn_global_load_lds(
        (const __attribute__((address_space(1))) unsigned int*)(a2 + ci0),
        (__attribute__((address_space(3))) unsigned int*)(dst + ((tid + 512) << 3)), 16, 0, 0);
}

// compute one ky-phase (static KY): 3 kx * 4 nt * 4 yr MFMAs (hi-only)
template<int KY>
__device__ __forceinline__ void conv_compute(const short* Ah, const short* Bb,
        f32x4 (&acc)[4][4], int lrow, int lch, int wy, int wc) {
#pragma unroll
    for (int kx = 0; kx < 3; ++kx) {
        int colL = lrow + kx;
        int asw = (lch ^ ((colL >> 1) & 3)) << 3;
        bf16x8 ahf[4];
#pragma unroll
        for (int yr = 0; yr < 4; ++yr) {
            int rr = wy * 4 + yr + KY;
            ahf[yr] = *(const bf16x8*)(Ah + (rr * 18 + colL) * 32 + asw);
        }
#pragma unroll
        for (int nt = 0; nt < 4; ++nt) {
            int col = wc * 64 + nt * 16 + lrow;
            int boff = (kx << 12) + (col << 5) + ((lch ^ ((col >> 1) & 3)) << 3);
            bf16x8 bhf = *(const bf16x8*)(Bb + boff);
#pragma unroll
            for (int yr = 0; yr < 4; ++yr)
                acc[yr][nt] = __builtin_amdgcn_mfma_f32_16x16x32_bf16(ahf[yr], bhf, acc[yr][nt], 0, 0, 0);
        }
    }
}

// Implicit-GEMM modulated conv, single-pass bf16 MFMA (ah*bh), async
// double-buffered staging via global_load_lds (no VGPR round-trip).
// LDS: A0/A1 768 slots, B0/B1 1536 slots, 16B each = 73728 B -> 2 blocks/CU.
// NOTE: no pointer-arrays into LDS (addrspacecast static-init bug) — ternary
// selects on the ping-pong bit instead.
__global__ __launch_bounds__(256) void conv_mfma(
        const unsigned short* __restrict__ xh,
        const unsigned short* __restrict__ wh,
        const unsigned short* __restrict__ zpage,
        const float* __restrict__ dm,
        const float* __restrict__ bias, unsigned short* __restrict__ convout) {
    extern __shared__ short lds[];

    int tid = threadIdx.x;
    int b = blockIdx.z;
    int co0 = blockIdx.y << 7;
    int sx = blockIdx.x & 3, sy = blockIdx.x >> 2;
    int x0 = sx << 4, y0 = sy << 3;
    int wid = tid >> 6, lane = tid & 63;
    int wy = wid >> 1, wc = wid & 1;
    int lrow = lane & 15, lch = lane >> 4;

    // B source offsets (ushort idx into wh). Slot u = tid+j*256 holds chunk
    // (u&3)^sw(co) of (kx,co), so reads at slot (kx*128+co)*4 + (lch^sw) get lch.
    int bsrc[6];
#pragma unroll
    for (int j = 0; j < 6; ++j) {
        int u = tid + (j << 8);
        int chunk = u & 3;
        int co = (u >> 2) & 127;
        int kx = u >> 9;
        int cs = chunk ^ ((co >> 1) & 3);
        bsrc[j] = (kx << 16) + ((co0 + co) << 8) + (cs << 3);
    }
    // A source pointers. Slot e = tid+k*256 (<720 real, rest pad) holds chunk
    // (e&3)^sw(col) of (row,col); OOB/pad lanes read the zero page.
    const unsigned short* ap0;
    const unsigned short* ap1;
    const unsigned short* ap2;
#pragma unroll
    for (int k = 0; k < 3; ++k) {
        int u = tid + (k << 8);
        int t2 = u >> 2;
        int col = t2 % 18, row = t2 / 18;
        int yy = y0 + row, xx = x0 + col;
        bool ok = (u < 720) && (yy < 64) && (xx < 64);
        int cs = (u & 3) ^ ((col >> 1) & 3);
        const unsigned short* p = ok ? xh + ((((b << 6) + yy) << 6) + xx) * 256 + (cs << 3) : zpage;
        if (k == 0) ap0 = p; else if (k == 1) ap1 = p; else ap2 = p;
    }

    f32x4 acc[4][4];
#pragma unroll
    for (int i = 0; i < 4; ++i)
#pragma unroll
        for (int j = 0; j < 4; ++j) acc[i][j] = (f32x4){0.f, 0.f, 0.f, 0.f};

    // prologue: stage ks=0 ky=0
    stage_a(ap0, ap1, ap2, lds, tid, 0);
    stage_b(wh, bsrc, lds + 12288, tid, 0);
    __syncthreads();

#pragma unroll 1
    for (int ks = 0; ks < 8; ++ks) {
        int ci0 = ks << 5;
        int ci0n = (ks + 1) << 5;   // ks=7: harmless garbage prefetch, never read
        int pb = ks & 1;
        short* Acur = lds + (pb ? 6144 : 0);
        short* Anxt = lds + (pb ? 0 : 6144);
        short* Bcur = lds + (pb ? 24576 : 12288);
        short* Balt = lds + (pb ? 12288 : 24576);
        // phase ky=0: stage ky=1 into Balt
        stage_b(wh, bsrc, Balt, tid, 196608 + ci0);
        conv_compute<0>(Acur, Bcur, acc, lrow, lch, wy, wc);
        __syncthreads();
        // phase ky=1: stage ky=2 into Bcur
        stage_b(wh, bsrc, Bcur, tid, 2 * 196608 + ci0);
        conv_compute<1>(Acur, Balt, acc, lrow, lch, wy, wc);
        __syncthreads();
        // phase ky=2: stage next-ks ky=0 into Balt, next A into Anxt
        stage_b(wh, bsrc, Balt, tid, ci0n);
        stage_a(ap0, ap1, ap2, Anxt, tid, ci0n);
        conv_compute<2>(Acur, Bcur, acc, lrow, lch, wy, wc);
        __syncthreads();
    }

    // epilogue: D row = x-pos = 4*lch + j, D col = co = 16*nt + lrow
    int xs4 = x0 + (lch << 2);
#pragma unroll
    for (int nt = 0; nt < 4; ++nt) {
        int co = co0 + wc * 64 + nt * 16 + lrow;
        float dmv = dm[(b << 8) + co];
        float bv = bias[co];
#pragma unroll
        for (int yr = 0; yr < 4; ++yr) {
            int y = y0 + wy * 4 + yr;
            if (y < HO) {
                ushort4 o;
                o.x = f2bf(acc[yr][nt][0] * dmv + bv);
                o.y = f2bf(acc[yr][nt][1] * dmv + bv);
                o.z = f2bf(acc[yr][nt][2] * dmv + bv);
                o.w = f2bf(acc[yr][nt][3] * dmv + bv);
                *(ushort4*)(convout + ((size_t)((b << 8) + co) * HO + y) * CSTRIDE + xs4) = o;
            }
        }
    }
}

// Fused upfirdn chain per (b,c) plane. 62x62 bf16 in -> 64x64 f32 out.
// (unchanged from round 7; see aliasing-safety comment there)
__global__ __launch_bounds__(256) void filter_kernel(
        const unsigned short* __restrict__ convout, const float* __restrict__ upf,
        const float* __restrict__ dnf, float* __restrict__ out) {
    __shared__ __align__(16) float lds0[13704];
    __shared__ __align__(16) float trow2[4][2][144];
    __shared__ float uf[12], df[12];
    float* cin  = lds0;
    float* bufA = lds0 + 4464;
    float* bufB = lds0;
    int tid = threadIdx.x;
    int p = blockIdx.x;
    const unsigned short* src = convout + (size_t)p * (HO * CSTRIDE);
    float* dst = out + (size_t)p * (64 * 64);
    if (tid < 12) { uf[tid] = upf[tid] * 2.f; df[tid] = dnf[tid]; }
    for (int idx = tid; idx < 62 * 16; idx += 256) {
        int y = idx >> 4, q = idx & 15;
        ushort4 v = *(const ushort4*)(src + y * CSTRIDE + q * 4);
        if (q < 15) {
            float4 f = make_float4(bf2f(v.x), bf2f(v.y), bf2f(v.z), bf2f(v.w));
            *(float4*)(cin + y * 72 + 4 + q * 4) = f;
        } else {
            *(float2*)(cin + y * 72 + 64) = make_float2(bf2f(v.x), bf2f(v.y));
        }
    }
    for (int idx = tid; idx < 62 * 8; idx += 256) {
        int y = idx >> 3, q = idx & 7;
        cin[y * 72 + (q < 4 ? q : 62 + q)] = 0.f;
    }
    for (int idx = tid; idx < 1056; idx += 256) {
        int r = idx / 132, cc = idx - r * 132;
        bufA[(r < 4 ? r : 62 + r) * 132 + cc] = 0.f;
    }
    __syncthreads();
    for (int task = tid; task < 62 * 16; task += 256) {
        int y = task >> 4, g = task & 15;
        const float* crow = cin + y * 72 + 4 * g;
        float xv[10];
#pragma unroll
        for (int t = 0; t < 10; ++t) xv[t] = crow[t];
        float* arow = bufA + (y + 4) * 132 + 8 * g;
#pragma unroll
        for (int dd = 0; dd < 4; ++dd) {
            float oe = 0.f, oo = 0.f;
#pragma unroll
            for (int v = 0; v < 6; ++v) {
                oe += uf[2 * v + 1] * xv[dd + 5 - v];
                oo += uf[2 * v] * xv[dd + 6 - v];
            }
            *(float2*)(arow + 2 * dd) = make_float2(oe, oo);
        }
    }
    __syncthreads();
    for (int idx = tid; idx < 325; idx += 256) bufB[idx] = 0.f;

    int wid = tid >> 6, lane = tid & 63;
    float* tr0 = &trow2[wid][0][0];
    float* tr1 = &trow2[wid][1][0];
    if (lane < 5) { tr0[lane] = 0.f; tr1[lane] = 0.f; }
    if (lane < 7) { tr0[133 + lane] = 0.f; tr1[133 + lane] = 0.f; }
    const float SQ2 = 1.4142135623730951f;
    float w0[7], w1[7];
#pragma unroll
    for (int d = 0; d < 7; ++d) {
        w0[d] = bufA[(wid + d) * 132 + lane];
        w1[d] = bufA[(wid + d) * 132 + lane + 64];
    }
    for (int it = 0; it < 16; ++it) {
        int n = 4 * it + wid;
        {
            float te0 = 0.f, to0 = 0.f, te1 = 0.f, to1 = 0.f;
#pragma unroll
            for (int d = 0; d < 6; ++d) { te0 += uf[11 - 2 * d] * w0[d]; te1 += uf[11 - 2 * d] * w1[d]; }
#pragma unroll
            for (int d = 1; d < 7; ++d) { to0 += uf[12 - 2 * d] * w0[d]; to1 += uf[12 - 2 * d] * w1[d]; }
            te0 = (te0 >= 0.f ? te0 : 0.2f * te0) * SQ2;
            to0 = (to0 >= 0.f ? to0 : 0.2f * to0) * SQ2;
            te1 = (te1 >= 0.f ? te1 : 0.2f * te1) * SQ2;
            to1 = (to1 >= 0.f ? to1 : 0.2f * to1) * SQ2;
            tr0[5 + lane] = te0;      tr1[5 + lane] = to0;
            tr0[69 + lane] = te1;     tr1[69 + lane] = to1;
        }
        __builtin_amdgcn_wave_barrier();
        {
            int xo = lane;
            const float2* a0 = (const float2*)&tr0[2 * xo];
            const float2* a1 = (const float2*)&tr1[2 * xo];
            float v0[12], v1[12];
#pragma unroll
            for (int q = 0; q < 6; ++q) {
                float2 u0 = a0[q], u1 = a1[q];
                v0[2 * q] = u0.x; v0[2 * q + 1] = u0.y;
                v1[2 * q] = u1.x; v1[2 * q + 1] = u1.y;
            }
            float s0 = 0.f, s1 = 0.f;
#pragma unroll
            for (int u = 0; u < 12; ++u) {
                s0 += df[u] * v0[11 - u];
                s1 += df[u] * v1[11 - u];
            }
            bufB[(2 * n + 5) * 65 + xo] = s0;
            bufB[(2 * n + 6) * 65 + xo] = s1;
        }
        if (it < 15) {
#pragma unroll
            for (int d = 0; d < 3; ++d) { w0[d] = w0[d + 4]; w1[d] = w1[d + 4]; }
#pragma unroll
            for (int d = 3; d < 7; ++d) {
                w0[d] = bufA[(n + 4 + d) * 132 + lane];
                w1[d] = bufA[(n + 4 + d) * 132 + lane + 64];
            }
        }
        if ((it & 3) == 3) __syncthreads();
        else __builtin_amdgcn_wave_barrier();
    }
    for (int idx = tid; idx < 64 * 64; idx += 256) {
        int yo = idx >> 6, xx = idx & 63;
        float acc2 = 0.f;
#pragma unroll
        for (int u = 0; u < 12; ++u) {
            int rr = 2 * yo + 6 - u;
            float v = (rr < 128) ? bufB[(rr + 5) * 65 + xx] : 0.f;
            acc2 += df[u] * v;
        }
        dst[idx] = acc2;
    }
}

extern "C" void kernel_launch(void* const* d_in, const int* in_sizes, int n_in,
                              void* d_out, int out_size, void* d_ws, size_t ws_size,
                              hipStream_t stream) {
    const float* input       = (const float*)d_in[0];
    const float* style       = (const float*)d_in[1];
    const float* conv_weight = (const float*)d_in[2];
    const float* mod_w       = (const float*)d_in[3];
    const float* mod_b       = (const float*)d_in[4];
    const float* bias        = (const float*)d_in[5];
    const float* up_filter   = (const float*)d_in[6];
    const float* down_filter = (const float*)d_in[7];
    float* ws  = (float*)d_ws;
    float* out = (float*)d_out;
    float* s_buf   = ws;
    float* dm      = ws + 2048;
    float* wsq     = ws + 4096;
    unsigned short* wh      = (unsigned short*)(ws + 69632);
    float* zpage            = ws + 364544;
    unsigned short* xh      = (unsigned short*)(ws + 659456);
    unsigned short* convout = (unsigned short*)(ws + 9048064);

    hipLaunchKernelGGL(mod_kernel, dim3(512), dim3(256), 0, stream, style, mod_w, mod_b, s_buf, zpage);
    hipLaunchKernelGGL(wsplit_kernel, dim3(256), dim3(256), 0, stream, conv_weight, wsq, wh);
    hipLaunchKernelGGL(demod_kernel, dim3(512), dim3(256), 0, stream, s_buf, wsq, dm);
    hipLaunchKernelGGL(xsplit_kernel, dim3(512), dim3(256), 0, stream, input, s_buf, xh);
    hipLaunchKernelGGL(conv_mfma, dim3(32, 2, 8), dim3(256), 73728, stream,
                       xh, wh, (const unsigned short*)zpage, dm, bias, convout);
    hipLaunchKernelGGL(filter_kernel, dim3(2048), dim3(256), 0, stream,
                       convout, up_filter, down_filter, out);
}